// Round 1
// baseline (119.951 us; speedup 1.0000x reference)
//
#include <hip/hip_runtime.h>
#include <math.h>

// SchurDecompositionLinear collapses algebraically:
//   apply_P right-multiplies by Q = H0*H1*...*H{n-1} (orthogonal, symmetric Hi)
//   W = (T*Q)*(I*Q)^T = T*Q*Q^T = T  (exact)
// T is block-diagonal 2x2: [[c,-s],[s,c]] * gamma per pair.
// So out = x @ T is an elementwise pairwise rotation — memory-bound streaming.
//
// This version: grid-stride with stride % F4_PER_ROW == 0, so each thread's
// column (and thus its two rotation pairs) is invariant -> compute c/s ONCE
// per thread in registers. No LDS, no __syncthreads, 8 loads in flight.

#define NCOLS 256
#define NPAIR (NCOLS / 2)       // 128
#define F4_PER_ROW (NCOLS / 4)  // 64
#define UNROLL 8

__global__ __launch_bounds__(256, 8) void schur_rot_kernel(
    const float4* __restrict__ x4,
    const float* __restrict__ theta,
    const float* __restrict__ gamma,
    float4* __restrict__ out4,
    int total4)
{
    const int tid    = blockIdx.x * blockDim.x + threadIdx.x;
    const int stride = gridDim.x * blockDim.x;   // multiple of 64 -> col4 invariant

    // Rotation coefficients for this thread's fixed column pair — registers only.
    const int col4 = tid & (F4_PER_ROW - 1);
    const int k0   = 2 * col4;
    const float th0 = theta[k0],     th1 = theta[k0 + 1];
    const float g0  = gamma[k0],     g1  = gamma[k0 + 1];
    const float c0 = g0 * cosf(th0), s0 = g0 * sinf(th0);
    const float c1 = g1 * cosf(th1), s1 = g1 * sinf(th1);

    if (tid + (UNROLL - 1) * stride < total4) {
        // Fast path: full batch — issue all 8 loads before any compute/store.
        float4 v[UNROLL];
        #pragma unroll
        for (int j = 0; j < UNROLL; ++j)
            v[j] = x4[tid + j * stride];
        #pragma unroll
        for (int j = 0; j < UNROLL; ++j) {
            float4 o;
            o.x = c0 * v[j].x + s0 * v[j].y;
            o.y = c0 * v[j].y - s0 * v[j].x;
            o.z = c1 * v[j].z + s1 * v[j].w;
            o.w = c1 * v[j].w - s1 * v[j].z;
            out4[tid + j * stride] = o;
        }
    } else {
        // Tail path: bounds-checked grid-stride loop.
        for (int i = tid; i < total4; i += stride) {
            float4 v = x4[i];
            float4 o;
            o.x = c0 * v.x + s0 * v.y;
            o.y = c0 * v.y - s0 * v.x;
            o.z = c1 * v.z + s1 * v.w;
            o.w = c1 * v.w - s1 * v.z;
            out4[i] = o;
        }
    }
}

extern "C" void kernel_launch(void* const* d_in, const int* in_sizes, int n_in,
                              void* d_out, int out_size, void* d_ws, size_t ws_size,
                              hipStream_t stream) {
    const float* x     = (const float*)d_in[0];   // [rows, 256]
    // d_in[1] = U  — unused: it cancels exactly (Q*Q^T = I)
    const float* theta = (const float*)d_in[2];   // [128]
    const float* gamma = (const float*)d_in[3];   // [128]
    float* out = (float*)d_out;

    int total  = in_sizes[0];          // rows * 256
    int total4 = total / 4;            // float4 count

    const int block = 256;
    const long long per = (long long)block * UNROLL;
    int grid = (int)(((long long)total4 + per - 1) / per);  // 2048 @ 65536 rows
    if (grid < 1) grid = 1;

    schur_rot_kernel<<<grid, block, 0, stream>>>(
        (const float4*)x, theta, gamma, (float4*)out, total4);
}